// Round 4
// baseline (11507.961 us; speedup 1.0000x reference)
//
#include <hip/hip_runtime.h>
#include <hip/hip_bf16.h>

using bf16 = __hip_bfloat16;

__device__ __forceinline__ float toF(float x) { return x; }
__device__ __forceinline__ float toF(bf16 x) { return __bfloat162float(x); }

template <typename T> __device__ __forceinline__ T fromF(float x);
template <> __device__ __forceinline__ float fromF<float>(float x) { return x; }
template <> __device__ __forceinline__ bf16 fromF<bf16>(float x) { return __float2bfloat16(x); }

// ---------------------------------------------------------------------------
// Tiled GEMM: C(M,N) = A(M,K) @ W(K,N) + bias(N) [+res] [ReLU]
//  A: TA (fp32 input or bf16 ws), W/bias: fp32 (model inputs), res: TR,
//  C: TO. fp32 accumulate.
//  HEADED: W is (H, K, 64) head-stacked; tiles are 64-wide so each block
//  maps to exactly one head (head = n0/64, ldb = 64).
//  64x64 tile / 256 threads / BK=16 / 4x4 per thread.
// ---------------------------------------------------------------------------
template <typename TA, typename TR, typename TO, bool HEADED, bool RELU, bool HASRES>
__global__ __launch_bounds__(256) void gemm_k(
    const TA* __restrict__ A, const float* __restrict__ W,
    const float* __restrict__ bias, const TR* __restrict__ res,
    TO* __restrict__ C, int M, int N, int K)
{
    __shared__ float As[16][65];   // As[k][m]
    __shared__ float Bs[16][65];   // Bs[k][n]

    const int tid = threadIdx.x;
    const int tx = tid & 15, ty = tid >> 4;
    const int n0 = blockIdx.x * 64, m0 = blockIdx.y * 64;

    const float* Wb;
    int ldb;
    if constexpr (HEADED) { Wb = W + (size_t)(n0 >> 6) * (size_t)K * 64; ldb = 64; }
    else                  { Wb = W + n0; ldb = N; }

    float acc[4][4];
#pragma unroll
    for (int i = 0; i < 4; i++)
#pragma unroll
        for (int j = 0; j < 4; j++) acc[i][j] = 0.f;

    for (int k0 = 0; k0 < K; k0 += 16) {
#pragma unroll
        for (int i = 0; i < 4; i++) {            // A tile: 64 rows x 16 k
            int idx = tid + i * 256;
            int r = idx >> 4, c = idx & 15;
            As[c][r] = toF(A[(size_t)(m0 + r) * K + (k0 + c)]);
        }
#pragma unroll
        for (int i = 0; i < 4; i++) {            // W tile: 16 k x 64 cols
            int idx = tid + i * 256;
            int r = idx >> 6, c = idx & 63;
            Bs[r][c] = Wb[(size_t)(k0 + r) * ldb + c];
        }
        __syncthreads();
#pragma unroll
        for (int kk = 0; kk < 16; kk++) {
            float a[4], b[4];
#pragma unroll
            for (int i = 0; i < 4; i++) a[i] = As[kk][ty * 4 + i];
#pragma unroll
            for (int j = 0; j < 4; j++) b[j] = Bs[kk][tx * 4 + j];
#pragma unroll
            for (int i = 0; i < 4; i++)
#pragma unroll
                for (int j = 0; j < 4; j++) acc[i][j] = fmaf(a[i], b[j], acc[i][j]);
        }
        __syncthreads();
    }

#pragma unroll
    for (int i = 0; i < 4; i++) {
        int m = m0 + ty * 4 + i;
#pragma unroll
        for (int j = 0; j < 4; j++) {
            int n = n0 + tx * 4 + j;
            float v = acc[i][j] + bias[n];
            if constexpr (HASRES) v += toF(res[(size_t)m * N + n]);
            if constexpr (RELU) v = v > 0.f ? v : 0.f;
            C[(size_t)m * N + n] = fromF<TO>(v);
        }
    }
}

// ---------------------------------------------------------------------------
// Attention: one block per (q, h, b). Q/K/V/O are bf16 ws (B, S, H*64).
// Causal handled analytically by bounding k < q+1 (identical to ref's -1e9
// fill: masked logits' exp underflows to exactly 0 in fp32).
// ---------------------------------------------------------------------------
template <bool CAUSAL>
__global__ __launch_bounds__(256) void attn_k(
    const bf16* __restrict__ Q, const bf16* __restrict__ K,
    const bf16* __restrict__ V, bf16* __restrict__ O, int S)
{
    const int qi = blockIdx.x, h = blockIdx.y, b = blockIdx.z;
    const int H64 = gridDim.y * 64;
    const int tid = threadIdx.x;
    const int lane = tid & 63, wave = tid >> 6;
    const int kmax = CAUSAL ? (qi + 1) : S;

    __shared__ float qs[64];
    __shared__ float sc[1024];
    __shared__ float red[256];
    __shared__ float part[4][64];

    const size_t rowQ = ((size_t)b * S + qi) * H64 + h * 64;
    const size_t baseK = (size_t)b * S * H64 + h * 64;

    if (tid < 64) qs[tid] = toF(Q[rowQ + tid]);
    __syncthreads();

    // scores: one wave per k row, coalesced 64-lane read + shuffle reduce
    const float scale = 0.125f;
    for (int k = wave; k < kmax; k += 4) {
        float v = qs[lane] * toF(K[baseK + (size_t)k * H64 + lane]);
#pragma unroll
        for (int off = 32; off > 0; off >>= 1) v += __shfl_xor(v, off);
        if (lane == 0) sc[k] = v * scale;
    }
    __syncthreads();

    // softmax over sc[0..kmax)
    float mloc = -1e30f;
    for (int k = tid; k < kmax; k += 256) mloc = fmaxf(mloc, sc[k]);
    red[tid] = mloc;
    __syncthreads();
    for (int t = 128; t > 0; t >>= 1) {
        if (tid < t) red[tid] = fmaxf(red[tid], red[tid + t]);
        __syncthreads();
    }
    const float mx = red[0];
    __syncthreads();

    float sum = 0.f;
    for (int k = tid; k < kmax; k += 256) {
        float e = expf(sc[k] - mx);
        sc[k] = e;
        sum += e;
    }
    red[tid] = sum;
    __syncthreads();
    for (int t = 128; t > 0; t >>= 1) {
        if (tid < t) red[tid] += red[tid + t];
        __syncthreads();
    }
    const float inv = 1.f / red[0];
    __syncthreads();

    // PV: thread (wave, lane) -> k-chunk 'wave', out element 'lane' (coalesced V)
    float acc = 0.f;
    for (int k = wave; k < kmax; k += 4)
        acc += sc[k] * toF(V[baseK + (size_t)k * H64 + lane]);
    part[wave][lane] = acc;
    __syncthreads();
    if (wave == 0)
        O[rowQ + lane] = fromF<bf16>(
            (part[0][lane] + part[1][lane] + part[2][lane] + part[3][lane]) * inv);
}

// ---------------------------------------------------------------------------
// LayerNorm (ddof=1, eps=1e-12): one block per row of D=1024. X fp32,
// g/b fp32 (model inputs), output TO (bf16 ws or fp32 d_out).
// ---------------------------------------------------------------------------
template <typename TO>
__global__ __launch_bounds__(256) void ln_k(
    const float* __restrict__ X, const float* __restrict__ g,
    const float* __restrict__ bb, TO* __restrict__ O, int D)
{
    const int row = blockIdx.x;
    const int tid = threadIdx.x;
    __shared__ float xs[1024];
    __shared__ float red[256];
    const float* x = X + (size_t)row * D;

    float s = 0.f;
    for (int i = tid; i < D; i += 256) { float v = x[i]; xs[i] = v; s += v; }
    red[tid] = s;
    __syncthreads();
    for (int t = 128; t > 0; t >>= 1) {
        if (tid < t) red[tid] += red[tid + t];
        __syncthreads();
    }
    const float mean = red[0] / (float)D;
    __syncthreads();

    float s2 = 0.f;
    for (int i = tid; i < D; i += 256) { float d = xs[i] - mean; s2 += d * d; }
    red[tid] = s2;
    __syncthreads();
    for (int t = 128; t > 0; t >>= 1) {
        if (tid < t) red[tid] += red[tid + t];
        __syncthreads();
    }
    const float rstd = rsqrtf(red[0] / (float)(D - 1) + 1e-12f);

    TO* o = O + (size_t)row * D;
    for (int i = tid; i < D; i += 256)
        o[i] = fromF<TO>(g[i] * (xs[i] - mean) * rstd + bb[i]);
}

// ---------------------------------------------------------------------------
extern "C" void kernel_launch(void* const* d_in, const int* in_sizes, int n_in,
                              void* d_out, int out_size, void* d_ws, size_t ws_size,
                              hipStream_t stream)
{
    const int Bb = 4, S = 1024, D = 1024, F = 4096;
    const int M = Bb * S;  // 4096 tokens
    const int H = 16;

    const float* dec = (const float*)d_in[0];
    const float* enc = (const float*)d_in[1];

    // Defensive: mask (B*S*S = 4,194,304 elems) may or may not be at index 2.
    int base = 2;
    if (n_in >= 29 && in_sizes[2] == Bb * S * S) base = 3;  // mask present

    const float* sa_wq = (const float*)d_in[base + 0];
    const float* sa_wk = (const float*)d_in[base + 1];
    const float* sa_wv = (const float*)d_in[base + 2];
    const float* sa_bq = (const float*)d_in[base + 3];
    const float* sa_bk = (const float*)d_in[base + 4];
    const float* sa_bv = (const float*)d_in[base + 5];
    const float* sa_wo = (const float*)d_in[base + 6];
    const float* sa_bo = (const float*)d_in[base + 7];
    const float* ca_wq = (const float*)d_in[base + 8];
    const float* ca_wk = (const float*)d_in[base + 9];
    const float* ca_wv = (const float*)d_in[base + 10];
    const float* ca_bq = (const float*)d_in[base + 11];
    const float* ca_bk = (const float*)d_in[base + 12];
    const float* ca_bv = (const float*)d_in[base + 13];
    const float* ca_wo = (const float*)d_in[base + 14];
    const float* ca_bo = (const float*)d_in[base + 15];
    const float* ff_w1 = (const float*)d_in[base + 16];
    const float* ff_b1 = (const float*)d_in[base + 17];
    const float* ff_w2 = (const float*)d_in[base + 18];
    const float* ff_b2 = (const float*)d_in[base + 19];
    const float* ln1_g = (const float*)d_in[base + 20];
    const float* ln1_b = (const float*)d_in[base + 21];
    const float* ln2_g = (const float*)d_in[base + 22];
    const float* ln2_b = (const float*)d_in[base + 23];
    const float* ln3_g = (const float*)d_in[base + 24];
    const float* ln3_b = (const float*)d_in[base + 25];

    // Workspace (64 MiB total):
    //   SUM  fp32  E  [ 0,16M)  pre-LN residual sum (precision-critical)
    //   O1   bf16  E  [16M,24M)
    //   O2   bf16  E  [24M,32M)
    //   Q    bf16  E  [32M,40M)
    //   K    bf16  E  [40M,48M)
    //   V    bf16  E  [48M,56M)
    //   AO   bf16  E  [56M,64M)
    //   HID  bf16 4E  overlays [32M,64M) (Q..AO dead during FFN)
    const size_t E = (size_t)M * D;  // 4,194,304
    float* SUM = (float*)d_ws;
    bf16* O1 = (bf16*)(SUM + E);
    bf16* O2 = O1 + E;
    bf16* Q  = O2 + E;
    bf16* Kb = Q + E;
    bf16* Vb = Kb + E;
    bf16* AO = Vb + E;
    bf16* HID = Q;  // M*F bf16 overlay

    dim3 blk(256);
    dim3 gP(D / 64, M / 64);   // N=1024 GEMMs
    dim3 gF(F / 64, M / 64);   // N=4096 GEMM
    dim3 gA(S, H, Bb);

    // --- self-attention ---
    gemm_k<float, float, bf16, true, false, false><<<gP, blk, 0, stream>>>(dec, sa_wq, sa_bq, (const float*)nullptr, Q,  M, D, D);
    gemm_k<float, float, bf16, true, false, false><<<gP, blk, 0, stream>>>(dec, sa_wk, sa_bk, (const float*)nullptr, Kb, M, D, D);
    gemm_k<float, float, bf16, true, false, false><<<gP, blk, 0, stream>>>(dec, sa_wv, sa_bv, (const float*)nullptr, Vb, M, D, D);
    attn_k<true><<<gA, blk, 0, stream>>>(Q, Kb, Vb, AO, S);
    gemm_k<bf16, float, float, false, false, true><<<gP, blk, 0, stream>>>(AO, sa_wo, sa_bo, dec, SUM, M, D, D);
    ln_k<bf16><<<M, blk, 0, stream>>>(SUM, ln1_g, ln1_b, O1, D);

    // --- cross-attention ---
    gemm_k<bf16, float, bf16, true, false, false><<<gP, blk, 0, stream>>>(O1,  ca_wq, ca_bq, (const float*)nullptr, Q,  M, D, D);
    gemm_k<float, float, bf16, true, false, false><<<gP, blk, 0, stream>>>(enc, ca_wk, ca_bk, (const float*)nullptr, Kb, M, D, D);
    gemm_k<float, float, bf16, true, false, false><<<gP, blk, 0, stream>>>(enc, ca_wv, ca_bv, (const float*)nullptr, Vb, M, D, D);
    attn_k<false><<<gA, blk, 0, stream>>>(Q, Kb, Vb, AO, S);
    gemm_k<bf16, bf16, float, false, false, true><<<gP, blk, 0, stream>>>(AO, ca_wo, ca_bo, O1, SUM, M, D, D);
    ln_k<bf16><<<M, blk, 0, stream>>>(SUM, ln2_g, ln2_b, O2, D);

    // --- FFN ---
    gemm_k<bf16, float, bf16, false, true, false><<<gF, blk, 0, stream>>>(O2, ff_w1, ff_b1, (const float*)nullptr, HID, M, F, D);
    gemm_k<bf16, bf16, float, false, false, true><<<gP, blk, 0, stream>>>(HID, ff_w2, ff_b2, O2, SUM, M, D, F);
    ln_k<float><<<M, blk, 0, stream>>>(SUM, ln3_g, ln3_b, (float*)d_out, D);
}

// Round 6
// 3039.402 us; speedup vs baseline: 3.7863x; 3.7863x over previous
//
#include <hip/hip_runtime.h>
#include <hip/hip_bf16.h>

using bf16 = __hip_bfloat16;
typedef __attribute__((ext_vector_type(8))) short bf16x8;
typedef __attribute__((ext_vector_type(4))) float f32x4;

__device__ __forceinline__ float toF(float x) { return x; }
__device__ __forceinline__ float toF(bf16 x) { return __bfloat162float(x); }

template <typename T> __device__ __forceinline__ T fromF(float x);
template <> __device__ __forceinline__ float fromF<float>(float x) { return x; }
template <> __device__ __forceinline__ bf16 fromF<bf16>(float x) { return __float2bfloat16(x); }

__device__ __forceinline__ unsigned short f2bu(float f) {
    bf16 h = __float2bfloat16(f);
    return *reinterpret_cast<unsigned short*>(&h);
}

// ---------------------------------------------------------------------------
// Tiled GEMM: C(M,N) = A(M,K) @ W(K,N) + bias(N) [+res] [ReLU]
//  TRANSC: write C transposed per batch as Ct[(b*1024 + n)*1024 + s]
//  (b = m>>10, s = m&1023) -- used for V so attention reads V^T coalesced.
// ---------------------------------------------------------------------------
template <typename TA, typename TR, typename TO, bool HEADED, bool RELU, bool HASRES, bool TRANSC = false>
__global__ __launch_bounds__(256) void gemm_k(
    const TA* __restrict__ A, const float* __restrict__ W,
    const float* __restrict__ bias, const TR* __restrict__ res,
    TO* __restrict__ C, int M, int N, int K)
{
    __shared__ float As[16][65];   // As[k][m]
    __shared__ float Bs[16][65];   // Bs[k][n]

    const int tid = threadIdx.x;
    const int tx = tid & 15, ty = tid >> 4;
    const int n0 = blockIdx.x * 64, m0 = blockIdx.y * 64;

    const float* Wb;
    int ldb;
    if constexpr (HEADED) { Wb = W + (size_t)(n0 >> 6) * (size_t)K * 64; ldb = 64; }
    else                  { Wb = W + n0; ldb = N; }

    float acc[4][4];
#pragma unroll
    for (int i = 0; i < 4; i++)
#pragma unroll
        for (int j = 0; j < 4; j++) acc[i][j] = 0.f;

    for (int k0 = 0; k0 < K; k0 += 16) {
#pragma unroll
        for (int i = 0; i < 4; i++) {            // A tile: 64 rows x 16 k
            int idx = tid + i * 256;
            int r = idx >> 4, c = idx & 15;
            As[c][r] = toF(A[(size_t)(m0 + r) * K + (k0 + c)]);
        }
#pragma unroll
        for (int i = 0; i < 4; i++) {            // W tile: 16 k x 64 cols
            int idx = tid + i * 256;
            int r = idx >> 6, c = idx & 63;
            Bs[r][c] = Wb[(size_t)(k0 + r) * ldb + c];
        }
        __syncthreads();
#pragma unroll
        for (int kk = 0; kk < 16; kk++) {
            float a[4], b[4];
#pragma unroll
            for (int i = 0; i < 4; i++) a[i] = As[kk][ty * 4 + i];
#pragma unroll
            for (int j = 0; j < 4; j++) b[j] = Bs[kk][tx * 4 + j];
#pragma unroll
            for (int i = 0; i < 4; i++)
#pragma unroll
                for (int j = 0; j < 4; j++) acc[i][j] = fmaf(a[i], b[j], acc[i][j]);
        }
        __syncthreads();
    }

#pragma unroll
    for (int i = 0; i < 4; i++) {
        int m = m0 + ty * 4 + i;
#pragma unroll
        for (int j = 0; j < 4; j++) {
            int n = n0 + tx * 4 + j;
            float v = acc[i][j] + bias[n];
            if constexpr (HASRES) v += toF(res[(size_t)m * N + n]);
            if constexpr (RELU) v = v > 0.f ? v : 0.f;
            if constexpr (TRANSC)
                C[((size_t)(m >> 10) * 1024 + n) * 1024 + (m & 1023)] = fromF<TO>(v);
            else
                C[(size_t)m * N + n] = fromF<TO>(v);
        }
    }
}

// ---------------------------------------------------------------------------
// Flash attention, MFMA 16x16x32 bf16.
//  Q, K: token-major bf16 (b, s, h*64+dh). Vt: transposed bf16 (b*1024 + h*64+dh, s).
//  O: token-major bf16. One block per (q-tile of 64, h, b); wave w owns 16 queries.
//  Verified layouts (m89/m120): C/D col=lane&15, row=quad*4+reg;
//  A[m=lane&15][k=quad*8+j]; B[n=lane&15][k=quad*8+j].
// ---------------------------------------------------------------------------
template <bool CAUSAL>
__global__ __launch_bounds__(256) void fattn_k(
    const unsigned short* __restrict__ Q, const unsigned short* __restrict__ K,
    const unsigned short* __restrict__ Vt, unsigned short* __restrict__ O, int S)
{
    const int qt = blockIdx.x, h = blockIdx.y, b = blockIdx.z;
    const int H64 = 1024;
    const int tid = threadIdx.x;
    const int w = tid >> 6, lane = tid & 63;
    const int quad = lane >> 4, col = lane & 15;

    __shared__ __align__(16) unsigned short Ks[64 * 72];   // [key][dh]
    __shared__ __align__(16) unsigned short Vs[64 * 72];   // [dh][key]
    __shared__ __align__(16) unsigned short Ps[4 * 16 * 72]; // per-wave P tiles

    // Q fragments (held for the whole kernel)
    const int qBase = qt * 64 + w * 16;
    const size_t qrow = ((size_t)b * S + qBase + col) * H64 + h * 64;
    const bf16x8 qf0 = *(const bf16x8*)(Q + qrow + quad * 8);
    const bf16x8 qf1 = *(const bf16x8*)(Q + qrow + quad * 8 + 32);

    f32x4 o[4];
#pragma unroll
    for (int g = 0; g < 4; g++) o[g] = (f32x4){0.f, 0.f, 0.f, 0.f};
    float m_run[4], l_run[4];
#pragma unroll
    for (int r = 0; r < 4; r++) { m_run[r] = -1e30f; l_run[r] = 0.f; }

    const int skey = tid >> 2;          // 0..63: key row (K) / dh row (Vt)
    const int sseg = (tid & 3) * 16;    // 16-elem segment -> two uint4 copies
    const size_t kgbase = (size_t)b * S * H64 + h * 64;
    const size_t vgbase = ((size_t)b * 1024 + h * 64) * (size_t)S;

    const int nkt = CAUSAL ? (qt + 1) : (S >> 6);
    const float scale = 0.125f;
    unsigned short* Pw = Ps + w * (16 * 72);

    for (int kt = 0; kt < nkt; kt++) {
        __syncthreads();
        // stage K tile [key][dh] and V^T tile [dh][key]: 16 elems (2x16B) per thread
        {
            const unsigned short* kg_ = K + kgbase + (size_t)(kt * 64 + skey) * H64;
            const unsigned short* vg_ = Vt + vgbase + (size_t)skey * S + kt * 64;
            *(uint4*)(Ks + skey * 72 + sseg)     = *(const uint4*)(kg_ + sseg);
            *(uint4*)(Ks + skey * 72 + sseg + 8) = *(const uint4*)(kg_ + sseg + 8);
            *(uint4*)(Vs + skey * 72 + sseg)     = *(const uint4*)(vg_ + sseg);
            *(uint4*)(Vs + skey * 72 + sseg + 8) = *(const uint4*)(vg_ + sseg + 8);
        }
        __syncthreads();

        // --- QK^T: 4 key-groups of 16, contraction 64 = 2 chained mfma ---
        f32x4 s[4];
#pragma unroll
        for (int kg = 0; kg < 4; kg++) {
            bf16x8 k0 = *(const bf16x8*)(Ks + (kg * 16 + col) * 72 + quad * 8);
            bf16x8 k1 = *(const bf16x8*)(Ks + (kg * 16 + col) * 72 + quad * 8 + 32);
            f32x4 acc = (f32x4){0.f, 0.f, 0.f, 0.f};
            acc = __builtin_amdgcn_mfma_f32_16x16x32_bf16(qf0, k0, acc, 0, 0, 0);
            acc = __builtin_amdgcn_mfma_f32_16x16x32_bf16(qf1, k1, acc, 0, 0, 0);
            s[kg] = acc;
        }

        // --- scale + causal mask ---
#pragma unroll
        for (int kg = 0; kg < 4; kg++)
#pragma unroll
            for (int r = 0; r < 4; r++) {
                float v = s[kg][r] * scale;
                if (CAUSAL) {
                    int key = kt * 64 + kg * 16 + col;
                    int q = qBase + quad * 4 + r;
                    if (key > q) v = -1e30f;
                }
                s[kg][r] = v;
            }

        // --- online softmax (per row = quad*4+r, reduce across 16 lanes) ---
#pragma unroll
        for (int r = 0; r < 4; r++) {
            float mx = fmaxf(fmaxf(s[0][r], s[1][r]), fmaxf(s[2][r], s[3][r]));
#pragma unroll
            for (int off = 1; off < 16; off <<= 1)
                mx = fmaxf(mx, __shfl_xor(mx, off));
            float mnew = fmaxf(m_run[r], mx);
            float ps = 0.f;
#pragma unroll
            for (int kg = 0; kg < 4; kg++) {
                float e = __expf(s[kg][r] - mnew);
                s[kg][r] = e;
                ps += e;
            }
#pragma unroll
            for (int off = 1; off < 16; off <<= 1)
                ps += __shfl_xor(ps, off);
            float alpha = __expf(m_run[r] - mnew);
            l_run[r] = l_run[r] * alpha + ps;
            m_run[r] = mnew;
#pragma unroll
            for (int g = 0; g < 4; g++) o[g][r] *= alpha;
        }

        // --- P: C/D layout -> LDS -> A layout (bf16) ---
#pragma unroll
        for (int kg = 0; kg < 4; kg++)
#pragma unroll
            for (int r = 0; r < 4; r++)
                Pw[(quad * 4 + r) * 72 + kg * 16 + col] = f2bu(s[kg][r]);
        __syncthreads();   // uniform; guards cross-lane P visibility

        bf16x8 p0 = *(const bf16x8*)(Pw + col * 72 + quad * 8);
        bf16x8 p1 = *(const bf16x8*)(Pw + col * 72 + quad * 8 + 32);

        // --- PV: O[16q x 64dh] accumulate ---
#pragma unroll
        for (int g = 0; g < 4; g++) {
            bf16x8 v0 = *(const bf16x8*)(Vs + (g * 16 + col) * 72 + quad * 8);
            bf16x8 v1 = *(const bf16x8*)(Vs + (g * 16 + col) * 72 + quad * 8 + 32);
            o[g] = __builtin_amdgcn_mfma_f32_16x16x32_bf16(p0, v0, o[g], 0, 0, 0);
            o[g] = __builtin_amdgcn_mfma_f32_16x16x32_bf16(p1, v1, o[g], 0, 0, 0);
        }
    }

    // --- epilogue: normalize by l, store token-major bf16 ---
    const size_t orow = ((size_t)b * S + qBase) * H64 + h * 64;
#pragma unroll
    for (int r = 0; r < 4; r++) {
        float inv = 1.f / l_run[r];
        int q = quad * 4 + r;
#pragma unroll
        for (int g = 0; g < 4; g++)
            O[orow + (size_t)q * H64 + g * 16 + col] = f2bu(o[g][r] * inv);
    }
}

// ---------------------------------------------------------------------------
// LayerNorm (ddof=1, eps=1e-12): one block per row of D=1024.
// ---------------------------------------------------------------------------
template <typename TO>
__global__ __launch_bounds__(256) void ln_k(
    const float* __restrict__ X, const float* __restrict__ g,
    const float* __restrict__ bb, TO* __restrict__ O, int D)
{
    const int row = blockIdx.x;
    const int tid = threadIdx.x;
    __shared__ float xs[1024];
    __shared__ float red[256];
    const float* x = X + (size_t)row * D;

    float s = 0.f;
    for (int i = tid; i < D; i += 256) { float v = x[i]; xs[i] = v; s += v; }
    red[tid] = s;
    __syncthreads();
    for (int t = 128; t > 0; t >>= 1) {
        if (tid < t) red[tid] += red[tid + t];
        __syncthreads();
    }
    const float mean = red[0] / (float)D;
    __syncthreads();

    float s2 = 0.f;
    for (int i = tid; i < D; i += 256) { float d = xs[i] - mean; s2 += d * d; }
    red[tid] = s2;
    __syncthreads();
    for (int t = 128; t > 0; t >>= 1) {
        if (tid < t) red[tid] += red[tid + t];
        __syncthreads();
    }
    const float rstd = rsqrtf(red[0] / (float)(D - 1) + 1e-12f);

    TO* o = O + (size_t)row * D;
    for (int i = tid; i < D; i += 256)
        o[i] = fromF<TO>(g[i] * (xs[i] - mean) * rstd + bb[i]);
}

// ---------------------------------------------------------------------------
extern "C" void kernel_launch(void* const* d_in, const int* in_sizes, int n_in,
                              void* d_out, int out_size, void* d_ws, size_t ws_size,
                              hipStream_t stream)
{
    const int Bb = 4, S = 1024, D = 1024, F = 4096;
    const int M = Bb * S;  // 4096 tokens
    const int H = 16;

    const float* dec = (const float*)d_in[0];
    const float* enc = (const float*)d_in[1];

    int base = 2;
    if (n_in >= 29 && in_sizes[2] == Bb * S * S) base = 3;  // mask present

    const float* sa_wq = (const float*)d_in[base + 0];
    const float* sa_wk = (const float*)d_in[base + 1];
    const float* sa_wv = (const float*)d_in[base + 2];
    const float* sa_bq = (const float*)d_in[base + 3];
    const float* sa_bk = (const float*)d_in[base + 4];
    const float* sa_bv = (const float*)d_in[base + 5];
    const float* sa_wo = (const float*)d_in[base + 6];
    const float* sa_bo = (const float*)d_in[base + 7];
    const float* ca_wq = (const float*)d_in[base + 8];
    const float* ca_wk = (const float*)d_in[base + 9];
    const float* ca_wv = (const float*)d_in[base + 10];
    const float* ca_bq = (const float*)d_in[base + 11];
    const float* ca_bk = (const float*)d_in[base + 12];
    const float* ca_bv = (const float*)d_in[base + 13];
    const float* ca_wo = (const float*)d_in[base + 14];
    const float* ca_bo = (const float*)d_in[base + 15];
    const float* ff_w1 = (const float*)d_in[base + 16];
    const float* ff_b1 = (const float*)d_in[base + 17];
    const float* ff_w2 = (const float*)d_in[base + 18];
    const float* ff_b2 = (const float*)d_in[base + 19];
    const float* ln1_g = (const float*)d_in[base + 20];
    const float* ln1_b = (const float*)d_in[base + 21];
    const float* ln2_g = (const float*)d_in[base + 22];
    const float* ln2_b = (const float*)d_in[base + 23];
    const float* ln3_g = (const float*)d_in[base + 24];
    const float* ln3_b = (const float*)d_in[base + 25];

    // Workspace (64 MiB):
    //   SUM fp32 E | O1 bf16 E | O2 bf16 E | Q bf16 E | K bf16 E | Vt bf16 E | AO bf16 E
    //   HID bf16 4E overlays [Q..AO] during FFN.
    const size_t E = (size_t)M * D;
    float* SUM = (float*)d_ws;
    bf16* O1 = (bf16*)(SUM + E);
    bf16* O2 = O1 + E;
    bf16* Q  = O2 + E;
    bf16* Kb = Q + E;
    bf16* Vt = Kb + E;
    bf16* AO = Vt + E;
    bf16* HID = Q;

    dim3 blk(256);
    dim3 gP(D / 64, M / 64);
    dim3 gF(F / 64, M / 64);
    dim3 gA(S / 64, H, Bb);

    // --- self-attention ---
    gemm_k<float, float, bf16, true, false, false><<<gP, blk, 0, stream>>>(dec, sa_wq, sa_bq, (const float*)nullptr, Q,  M, D, D);
    gemm_k<float, float, bf16, true, false, false><<<gP, blk, 0, stream>>>(dec, sa_wk, sa_bk, (const float*)nullptr, Kb, M, D, D);
    gemm_k<float, float, bf16, true, false, false, true><<<gP, blk, 0, stream>>>(dec, sa_wv, sa_bv, (const float*)nullptr, Vt, M, D, D);
    fattn_k<true><<<gA, blk, 0, stream>>>((const unsigned short*)Q, (const unsigned short*)Kb,
                                          (const unsigned short*)Vt, (unsigned short*)AO, S);
    gemm_k<bf16, float, float, false, false, true><<<gP, blk, 0, stream>>>(AO, sa_wo, sa_bo, dec, SUM, M, D, D);
    ln_k<bf16><<<M, blk, 0, stream>>>(SUM, ln1_g, ln1_b, O1, D);

    // --- cross-attention ---
    gemm_k<bf16, float, bf16, true, false, false><<<gP, blk, 0, stream>>>(O1,  ca_wq, ca_bq, (const float*)nullptr, Q,  M, D, D);
    gemm_k<float, float, bf16, true, false, false><<<gP, blk, 0, stream>>>(enc, ca_wk, ca_bk, (const float*)nullptr, Kb, M, D, D);
    gemm_k<float, float, bf16, true, false, false, true><<<gP, blk, 0, stream>>>(enc, ca_wv, ca_bv, (const float*)nullptr, Vt, M, D, D);
    fattn_k<false><<<gA, blk, 0, stream>>>((const unsigned short*)Q, (const unsigned short*)Kb,
                                           (const unsigned short*)Vt, (unsigned short*)AO, S);
    gemm_k<bf16, bf16, float, false, false, true><<<gP, blk, 0, stream>>>(AO, ca_wo, ca_bo, O1, SUM, M, D, D);
    ln_k<bf16><<<M, blk, 0, stream>>>(SUM, ln2_g, ln2_b, O2, D);

    // --- FFN ---
    gemm_k<bf16, float, bf16, false, true, false><<<gF, blk, 0, stream>>>(O2, ff_w1, ff_b1, (const float*)nullptr, HID, M, F, D);
    gemm_k<bf16, bf16, float, false, false, true><<<gP, blk, 0, stream>>>(HID, ff_w2, ff_b2, O2, SUM, M, D, F);
    ln_k<float><<<M, blk, 0, stream>>>(SUM, ln3_g, ln3_b, (float*)d_out, D);
}

// Round 7
// 726.591 us; speedup vs baseline: 15.8383x; 4.1831x over previous
//
#include <hip/hip_runtime.h>
#include <hip/hip_bf16.h>

using bf16 = __hip_bfloat16;
typedef __attribute__((ext_vector_type(8))) short bf16x8;
typedef __attribute__((ext_vector_type(4))) float f32x4;

__device__ __forceinline__ float toF(float x) { return x; }
__device__ __forceinline__ float toF(bf16 x) { return __bfloat162float(x); }

template <typename T> __device__ __forceinline__ T fromF(float x);
template <> __device__ __forceinline__ float fromF<float>(float x) { return x; }
template <> __device__ __forceinline__ bf16 fromF<bf16>(float x) { return __float2bfloat16(x); }

__device__ __forceinline__ unsigned short f2bu(float f) {
    bf16 h = __float2bfloat16(f);
    return *reinterpret_cast<unsigned short*>(&h);
}

// ---------------------------------------------------------------------------
// fp32 -> bf16 elementwise convert (vector 4/thread)
// ---------------------------------------------------------------------------
__global__ __launch_bounds__(256) void cvt_k(const float* __restrict__ X,
                                             unsigned short* __restrict__ Y, int n)
{
    int i = (blockIdx.x * 256 + threadIdx.x) * 4;
    if (i >= n) return;
    float4 v = *(const float4*)(X + i);
    ushort4 o;
    o.x = f2bu(v.x); o.y = f2bu(v.y); o.z = f2bu(v.z); o.w = f2bu(v.w);
    *(ushort4*)(Y + i) = o;
}

// ---------------------------------------------------------------------------
// Weight transpose: W fp32 (K,N) [or head-stacked (H,K,64), n=(h<<6)+dh]
//   -> Wt bf16 (N,K).  32x32 LDS tile, 256 threads (32 cols x 8 rows x 4 it).
// ---------------------------------------------------------------------------
template <bool HEADED>
__global__ __launch_bounds__(256) void wtrans_k(
    const float* __restrict__ W, unsigned short* __restrict__ Wt, int K, int N)
{
    __shared__ float t[32][33];
    const int k0 = blockIdx.x * 32, n0 = blockIdx.y * 32;
    const int tx = threadIdx.x & 31, ty = threadIdx.x >> 5;
#pragma unroll
    for (int i = 0; i < 4; i++) {
        int k = k0 + ty + 8 * i, n = n0 + tx;
        float v;
        if constexpr (HEADED) v = W[((size_t)(n >> 6) * K + k) * 64 + (n & 63)];
        else                  v = W[(size_t)k * N + n];
        t[ty + 8 * i][tx] = v;
    }
    __syncthreads();
#pragma unroll
    for (int i = 0; i < 4; i++)
        Wt[(size_t)(n0 + ty + 8 * i) * K + k0 + tx] = f2bu(t[tx][ty + 8 * i]);
}

// ---------------------------------------------------------------------------
// MFMA GEMM: C(M,N) = A(M,K)bf16 @ Bt(N,K)bf16^T + bias [+res] [ReLU] [TRANSC]
//  128x128 tile, BK=32, 256 threads (4 waves, each 64x64 = 4x4 mfma 16x16x32).
//  LDS [dim][k] pitch 56 elems (112 B: 16B-aligned rows, good bank spread).
// ---------------------------------------------------------------------------
template <typename TO, typename TR, bool RELU, bool HASRES, bool TRANSC>
__global__ __launch_bounds__(256) void gemm_mfma(
    const unsigned short* __restrict__ A, const unsigned short* __restrict__ Bt,
    const float* __restrict__ bias, const TR* __restrict__ res,
    TO* __restrict__ C, int M, int N, int K)
{
    constexpr int P = 56;
    __shared__ __align__(16) unsigned short As[128 * P];
    __shared__ __align__(16) unsigned short Bs[128 * P];

    const int tid = threadIdx.x;
    const int lane = tid & 63, wv = tid >> 6;
    const int quad = lane >> 4, col = lane & 15;
    const int m0 = blockIdx.y * 128, n0 = blockIdx.x * 128;
    const int wm = (wv >> 1) * 64, wn = (wv & 1) * 64;

    f32x4 acc[4][4];
#pragma unroll
    for (int i = 0; i < 4; i++)
#pragma unroll
        for (int j = 0; j < 4; j++) acc[i][j] = (f32x4){0.f, 0.f, 0.f, 0.f};

    const int r0 = tid >> 2;           // 0..63
    const int sg = (tid & 3) * 8;      // k-segment (8 elems)

    for (int k0 = 0; k0 < K; k0 += 32) {
        bf16x8 a0 = *(const bf16x8*)(A  + (size_t)(m0 + r0)      * K + k0 + sg);
        bf16x8 a1 = *(const bf16x8*)(A  + (size_t)(m0 + 64 + r0) * K + k0 + sg);
        bf16x8 b0 = *(const bf16x8*)(Bt + (size_t)(n0 + r0)      * K + k0 + sg);
        bf16x8 b1 = *(const bf16x8*)(Bt + (size_t)(n0 + 64 + r0) * K + k0 + sg);
        __syncthreads();
        *(bf16x8*)(As + r0 * P + sg)        = a0;
        *(bf16x8*)(As + (64 + r0) * P + sg) = a1;
        *(bf16x8*)(Bs + r0 * P + sg)        = b0;
        *(bf16x8*)(Bs + (64 + r0) * P + sg) = b1;
        __syncthreads();

        bf16x8 af[4], bf[4];
#pragma unroll
        for (int mi = 0; mi < 4; mi++)
            af[mi] = *(const bf16x8*)(As + (wm + mi * 16 + col) * P + quad * 8);
#pragma unroll
        for (int ni = 0; ni < 4; ni++)
            bf[ni] = *(const bf16x8*)(Bs + (wn + ni * 16 + col) * P + quad * 8);
#pragma unroll
        for (int mi = 0; mi < 4; mi++)
#pragma unroll
            for (int ni = 0; ni < 4; ni++)
                acc[mi][ni] = __builtin_amdgcn_mfma_f32_16x16x32_bf16(
                    af[mi], bf[ni], acc[mi][ni], 0, 0, 0);
    }

    // epilogue: m = m0+wm+mi*16+quad*4+r, n = n0+wn+ni*16+col
    float bv[4];
#pragma unroll
    for (int ni = 0; ni < 4; ni++) bv[ni] = bias[n0 + wn + ni * 16 + col];
#pragma unroll
    for (int mi = 0; mi < 4; mi++) {
#pragma unroll
        for (int r = 0; r < 4; r++) {
            int m = m0 + wm + mi * 16 + quad * 4 + r;
#pragma unroll
            for (int ni = 0; ni < 4; ni++) {
                int n = n0 + wn + ni * 16 + col;
                float v = acc[mi][ni][r] + bv[ni];
                if constexpr (HASRES) v += toF(res[(size_t)m * N + n]);
                if constexpr (RELU) v = v > 0.f ? v : 0.f;
                if constexpr (TRANSC)
                    C[((size_t)(m >> 10) * 1024 + n) * 1024 + (m & 1023)] = fromF<TO>(v);
                else
                    C[(size_t)m * N + n] = fromF<TO>(v);
            }
        }
    }
}

// ---------------------------------------------------------------------------
// Flash attention, MFMA 16x16x32 bf16 (unchanged from round 6 — verified).
// ---------------------------------------------------------------------------
template <bool CAUSAL>
__global__ __launch_bounds__(256) void fattn_k(
    const unsigned short* __restrict__ Q, const unsigned short* __restrict__ K,
    const unsigned short* __restrict__ Vt, unsigned short* __restrict__ O, int S)
{
    const int qt = blockIdx.x, h = blockIdx.y, b = blockIdx.z;
    const int H64 = 1024;
    const int tid = threadIdx.x;
    const int w = tid >> 6, lane = tid & 63;
    const int quad = lane >> 4, col = lane & 15;

    __shared__ __align__(16) unsigned short Ks[64 * 72];
    __shared__ __align__(16) unsigned short Vs[64 * 72];
    __shared__ __align__(16) unsigned short Ps[4 * 16 * 72];

    const int qBase = qt * 64 + w * 16;
    const size_t qrow = ((size_t)b * S + qBase + col) * H64 + h * 64;
    const bf16x8 qf0 = *(const bf16x8*)(Q + qrow + quad * 8);
    const bf16x8 qf1 = *(const bf16x8*)(Q + qrow + quad * 8 + 32);

    f32x4 o[4];
#pragma unroll
    for (int g = 0; g < 4; g++) o[g] = (f32x4){0.f, 0.f, 0.f, 0.f};
    float m_run[4], l_run[4];
#pragma unroll
    for (int r = 0; r < 4; r++) { m_run[r] = -1e30f; l_run[r] = 0.f; }

    const int skey = tid >> 2;
    const int sseg = (tid & 3) * 16;
    const size_t kgbase = (size_t)b * S * H64 + h * 64;
    const size_t vgbase = ((size_t)b * 1024 + h * 64) * (size_t)S;

    const int nkt = CAUSAL ? (qt + 1) : (S >> 6);
    const float scale = 0.125f;
    unsigned short* Pw = Ps + w * (16 * 72);

    for (int kt = 0; kt < nkt; kt++) {
        __syncthreads();
        {
            const unsigned short* kg_ = K + kgbase + (size_t)(kt * 64 + skey) * H64;
            const unsigned short* vg_ = Vt + vgbase + (size_t)skey * S + kt * 64;
            *(uint4*)(Ks + skey * 72 + sseg)     = *(const uint4*)(kg_ + sseg);
            *(uint4*)(Ks + skey * 72 + sseg + 8) = *(const uint4*)(kg_ + sseg + 8);
            *(uint4*)(Vs + skey * 72 + sseg)     = *(const uint4*)(vg_ + sseg);
            *(uint4*)(Vs + skey * 72 + sseg + 8) = *(const uint4*)(vg_ + sseg + 8);
        }
        __syncthreads();

        f32x4 s[4];
#pragma unroll
        for (int kg = 0; kg < 4; kg++) {
            bf16x8 k0 = *(const bf16x8*)(Ks + (kg * 16 + col) * 72 + quad * 8);
            bf16x8 k1 = *(const bf16x8*)(Ks + (kg * 16 + col) * 72 + quad * 8 + 32);
            f32x4 a = (f32x4){0.f, 0.f, 0.f, 0.f};
            a = __builtin_amdgcn_mfma_f32_16x16x32_bf16(qf0, k0, a, 0, 0, 0);
            a = __builtin_amdgcn_mfma_f32_16x16x32_bf16(qf1, k1, a, 0, 0, 0);
            s[kg] = a;
        }

#pragma unroll
        for (int kg = 0; kg < 4; kg++)
#pragma unroll
            for (int r = 0; r < 4; r++) {
                float v = s[kg][r] * scale;
                if (CAUSAL) {
                    int key = kt * 64 + kg * 16 + col;
                    int q = qBase + quad * 4 + r;
                    if (key > q) v = -1e30f;
                }
                s[kg][r] = v;
            }

#pragma unroll
        for (int r = 0; r < 4; r++) {
            float mx = fmaxf(fmaxf(s[0][r], s[1][r]), fmaxf(s[2][r], s[3][r]));
#pragma unroll
            for (int off = 1; off < 16; off <<= 1)
                mx = fmaxf(mx, __shfl_xor(mx, off));
            float mnew = fmaxf(m_run[r], mx);
            float ps = 0.f;
#pragma unroll
            for (int kg = 0; kg < 4; kg++) {
                float e = __expf(s[kg][r] - mnew);
                s[kg][r] = e;
                ps += e;
            }
#pragma unroll
            for (int off = 1; off < 16; off <<= 1)
                ps += __shfl_xor(ps, off);
            float alpha = __expf(m_run[r] - mnew);
            l_run[r] = l_run[r] * alpha + ps;
            m_run[r] = mnew;
#pragma unroll
            for (int g = 0; g < 4; g++) o[g][r] *= alpha;
        }

#pragma unroll
        for (int kg = 0; kg < 4; kg++)
#pragma unroll
            for (int r = 0; r < 4; r++)
                Pw[(quad * 4 + r) * 72 + kg * 16 + col] = f2bu(s[kg][r]);
        __syncthreads();

        bf16x8 p0 = *(const bf16x8*)(Pw + col * 72 + quad * 8);
        bf16x8 p1 = *(const bf16x8*)(Pw + col * 72 + quad * 8 + 32);

#pragma unroll
        for (int g = 0; g < 4; g++) {
            bf16x8 v0 = *(const bf16x8*)(Vs + (g * 16 + col) * 72 + quad * 8);
            bf16x8 v1 = *(const bf16x8*)(Vs + (g * 16 + col) * 72 + quad * 8 + 32);
            o[g] = __builtin_amdgcn_mfma_f32_16x16x32_bf16(p0, v0, o[g], 0, 0, 0);
            o[g] = __builtin_amdgcn_mfma_f32_16x16x32_bf16(p1, v1, o[g], 0, 0, 0);
        }
    }

    const size_t orow = ((size_t)b * S + qBase) * H64 + h * 64;
#pragma unroll
    for (int r = 0; r < 4; r++) {
        float inv = 1.f / l_run[r];
        int q = quad * 4 + r;
#pragma unroll
        for (int g = 0; g < 4; g++)
            O[orow + (size_t)q * H64 + g * 16 + col] = f2bu(o[g][r] * inv);
    }
}

// ---------------------------------------------------------------------------
// LayerNorm (ddof=1, eps=1e-12)
// ---------------------------------------------------------------------------
template <typename TO>
__global__ __launch_bounds__(256) void ln_k(
    const float* __restrict__ X, const float* __restrict__ g,
    const float* __restrict__ bb, TO* __restrict__ O, int D)
{
    const int row = blockIdx.x;
    const int tid = threadIdx.x;
    __shared__ float xs[1024];
    __shared__ float red[256];
    const float* x = X + (size_t)row * D;

    float s = 0.f;
    for (int i = tid; i < D; i += 256) { float v = x[i]; xs[i] = v; s += v; }
    red[tid] = s;
    __syncthreads();
    for (int t = 128; t > 0; t >>= 1) {
        if (tid < t) red[tid] += red[tid + t];
        __syncthreads();
    }
    const float mean = red[0] / (float)D;
    __syncthreads();

    float s2 = 0.f;
    for (int i = tid; i < D; i += 256) { float d = xs[i] - mean; s2 += d * d; }
    red[tid] = s2;
    __syncthreads();
    for (int t = 128; t > 0; t >>= 1) {
        if (tid < t) red[tid] += red[tid + t];
        __syncthreads();
    }
    const float rstd = rsqrtf(red[0] / (float)(D - 1) + 1e-12f);

    TO* o = O + (size_t)row * D;
    for (int i = tid; i < D; i += 256)
        o[i] = fromF<TO>(g[i] * (xs[i] - mean) * rstd + bb[i]);
}

// ---------------------------------------------------------------------------
extern "C" void kernel_launch(void* const* d_in, const int* in_sizes, int n_in,
                              void* d_out, int out_size, void* d_ws, size_t ws_size,
                              hipStream_t stream)
{
    const int Bb = 4, S = 1024, D = 1024, F = 4096;
    const int M = Bb * S;
    const int H = 16;

    const float* dec = (const float*)d_in[0];
    const float* enc = (const float*)d_in[1];

    int base = 2;
    if (n_in >= 29 && in_sizes[2] == Bb * S * S) base = 3;

    const float* sa_wq = (const float*)d_in[base + 0];
    const float* sa_wk = (const float*)d_in[base + 1];
    const float* sa_wv = (const float*)d_in[base + 2];
    const float* sa_bq = (const float*)d_in[base + 3];
    const float* sa_bk = (const float*)d_in[base + 4];
    const float* sa_bv = (const float*)d_in[base + 5];
    const float* sa_wo = (const float*)d_in[base + 6];
    const float* sa_bo = (const float*)d_in[base + 7];
    const float* ca_wq = (const float*)d_in[base + 8];
    const float* ca_wk = (const float*)d_in[base + 9];
    const float* ca_wv = (const float*)d_in[base + 10];
    const float* ca_bq = (const float*)d_in[base + 11];
    const float* ca_bk = (const float*)d_in[base + 12];
    const float* ca_bv = (const float*)d_in[base + 13];
    const float* ca_wo = (const float*)d_in[base + 14];
    const float* ca_bo = (const float*)d_in[base + 15];
    const float* ff_w1 = (const float*)d_in[base + 16];
    const float* ff_b1 = (const float*)d_in[base + 17];
    const float* ff_w2 = (const float*)d_in[base + 18];
    const float* ff_b2 = (const float*)d_in[base + 19];
    const float* ln1_g = (const float*)d_in[base + 20];
    const float* ln1_b = (const float*)d_in[base + 21];
    const float* ln2_g = (const float*)d_in[base + 22];
    const float* ln2_b = (const float*)d_in[base + 23];
    const float* ln3_g = (const float*)d_in[base + 24];
    const float* ln3_b = (const float*)d_in[base + 25];

    // ws (64 MiB): SUM fp32 E | O1 bf16 E | O2 bf16 E | Q | K | Vt | AO (bf16 E each)
    //   HID bf16 4E overlays [Q..AO] (FFN phase); decB overlays AO (pre-attn phase).
    // d_out (16 MiB fp32) doubles as scratch until the final LN:
    //   Wt bf16 [0,8MiB) per-GEMM transposed weight; encB bf16 [8,16MiB).
    const size_t E = (size_t)M * D;
    float* SUM = (float*)d_ws;
    bf16* O1 = (bf16*)(SUM + E);
    bf16* O2 = O1 + E;
    bf16* Q  = O2 + E;
    bf16* Kb = Q + E;
    bf16* Vt = Kb + E;
    bf16* AO = Vt + E;
    bf16* HID = Q;
    unsigned short* decB = (unsigned short*)AO;           // dead once fattn writes AO
    unsigned short* Wt   = (unsigned short*)d_out;        // 8 MiB slot
    unsigned short* encB = (unsigned short*)d_out + 4 * 1024 * 1024;

    dim3 blk(256);
    dim3 gP(D / 128, M / 128);    // N=1024 MFMA gemms: 8 x 32
    dim3 gF(F / 128, M / 128);    // N=4096: 32 x 32
    dim3 gA(S / 64, H, Bb);
    dim3 gT(D / 32, D / 32);      // (K/32, N/32) for K=N=1024
    dim3 gT1(D / 32, F / 32);     // ff_w1: K=1024, N=4096
    dim3 gT2(F / 32, D / 32);     // ff_w2: K=4096, N=1024

    // input converts
    cvt_k<<<M * D / 1024, blk, 0, stream>>>(dec, decB, M * D);
    cvt_k<<<M * D / 1024, blk, 0, stream>>>(enc, encB, M * D);

    // --- self-attention ---
    wtrans_k<true><<<gT, blk, 0, stream>>>(sa_wq, Wt, D, D);
    gemm_mfma<bf16, float, false, false, false><<<gP, blk, 0, stream>>>(decB, Wt, sa_bq, (const float*)nullptr, Q, M, D, D);
    wtrans_k<true><<<gT, blk, 0, stream>>>(sa_wk, Wt, D, D);
    gemm_mfma<bf16, float, false, false, false><<<gP, blk, 0, stream>>>(decB, Wt, sa_bk, (const float*)nullptr, Kb, M, D, D);
    wtrans_k<true><<<gT, blk, 0, stream>>>(sa_wv, Wt, D, D);
    gemm_mfma<bf16, float, false, false, true><<<gP, blk, 0, stream>>>(decB, Wt, sa_bv, (const float*)nullptr, Vt, M, D, D);
    fattn_k<true><<<gA, blk, 0, stream>>>((const unsigned short*)Q, (const unsigned short*)Kb,
                                          (const unsigned short*)Vt, (unsigned short*)AO, S);
    wtrans_k<false><<<gT, blk, 0, stream>>>(sa_wo, Wt, D, D);
    gemm_mfma<float, float, false, true, false><<<gP, blk, 0, stream>>>((const unsigned short*)AO, Wt, sa_bo, dec, SUM, M, D, D);
    ln_k<bf16><<<M, blk, 0, stream>>>(SUM, ln1_g, ln1_b, O1, D);

    // --- cross-attention ---
    wtrans_k<true><<<gT, blk, 0, stream>>>(ca_wq, Wt, D, D);
    gemm_mfma<bf16, float, false, false, false><<<gP, blk, 0, stream>>>((const unsigned short*)O1, Wt, ca_bq, (const float*)nullptr, Q, M, D, D);
    wtrans_k<true><<<gT, blk, 0, stream>>>(ca_wk, Wt, D, D);
    gemm_mfma<bf16, float, false, false, false><<<gP, blk, 0, stream>>>(encB, Wt, ca_bk, (const float*)nullptr, Kb, M, D, D);
    wtrans_k<true><<<gT, blk, 0, stream>>>(ca_wv, Wt, D, D);
    gemm_mfma<bf16, float, false, false, true><<<gP, blk, 0, stream>>>(encB, Wt, ca_bv, (const float*)nullptr, Vt, M, D, D);
    fattn_k<false><<<gA, blk, 0, stream>>>((const unsigned short*)Q, (const unsigned short*)Kb,
                                           (const unsigned short*)Vt, (unsigned short*)AO, S);
    wtrans_k<false><<<gT, blk, 0, stream>>>(ca_wo, Wt, D, D);
    gemm_mfma<float, bf16, false, true, false><<<gP, blk, 0, stream>>>((const unsigned short*)AO, Wt, ca_bo, O1, SUM, M, D, D);
    ln_k<bf16><<<M, blk, 0, stream>>>(SUM, ln2_g, ln2_b, O2, D);

    // --- FFN ---
    wtrans_k<false><<<gT1, blk, 0, stream>>>(ff_w1, Wt, D, F);
    gemm_mfma<bf16, float, true, false, false><<<gF, blk, 0, stream>>>((const unsigned short*)O2, Wt, ff_b1, (const float*)nullptr, HID, M, F, D);
    wtrans_k<false><<<gT2, blk, 0, stream>>>(ff_w2, Wt, F, D);
    gemm_mfma<float, bf16, false, true, false><<<gP, blk, 0, stream>>>((const unsigned short*)HID, Wt, ff_b2, O2, SUM, M, D, F);
    ln_k<float><<<M, blk, 0, stream>>>(SUM, ln3_g, ln3_b, (float*)d_out, D);
}